// Round 8
// baseline (636.975 us; speedup 1.0000x reference)
//
#include <hip/hip_runtime.h>

// ---------- types ----------
typedef __attribute__((ext_vector_type(8))) short bf16x8;
typedef __attribute__((ext_vector_type(4))) float f32x4;

static __device__ __forceinline__ unsigned short f2bf(float x) {
    unsigned int u = __float_as_uint(x);
    u += 0x7fffu + ((u >> 16) & 1u);   // RTNE, finite inputs
    return (unsigned short)(u >> 16);
}

static __device__ __forceinline__ float selq(const f32x4* a, int q) {
    return (q == 0) ? a[0][0] : (q == 1) ? a[1][0] : (q == 2) ? a[2][0] : a[3][0];
}

// Workgroup barrier WITHOUT vmcnt drain: LDS ordering only.
static __device__ __forceinline__ void barrier_lds_only() {
    __asm__ volatile("s_waitcnt lgkmcnt(0)\n\ts_barrier" ::: "memory");
}

// ---------- K0: four fp32->bf16 transposes in one launch ----------
__global__ void transpose4(const float* __restrict__ s0, const float* __restrict__ s1,
                           const float* __restrict__ s2, const float* __restrict__ s3,
                           unsigned short* __restrict__ d0, unsigned short* __restrict__ d1,
                           unsigned short* __restrict__ d2, unsigned short* __restrict__ d3) {
    int which = blockIdx.y;
    const float* src = which == 0 ? s0 : which == 1 ? s1 : which == 2 ? s2 : s3;
    unsigned short* dst = which == 0 ? d0 : which == 1 ? d1 : which == 2 ? d2 : d3;
    int K = (which == 0) ? 512 : 256;
    int idx = blockIdx.x * 256 + threadIdx.x;
    if (idx >= K * 256) return;
    int k = idx >> 8;          // N = 256
    int n = idx & 255;
    dst[n * K + k] = f2bf(src[idx]);
}

// ---------- K1 GEMM: C[M,N] = A[M,K] @ Bt[N,K]^T + bias, bf16 MFMA ----------
// Software-pipelined: tile k+1's global loads (incl. the emb gather) issue right
// after the barrier, hiding HBM latency under the MFMAs of tile k.
template<bool GATHER>
__global__ __launch_bounds__(256, 4) void gemm_mfma(
    const void* __restrict__ Aptr, const int* __restrict__ tokens,
    const unsigned short* __restrict__ Bt, const float* __restrict__ bias,
    float* __restrict__ C, int M, int N, int K)
{
    const int bn0 = blockIdx.x * 64;
    const int m0  = blockIdx.y * 64;
    const int tid = threadIdx.x;

    __shared__ unsigned short As[64 * 40];
    __shared__ unsigned short Bs[64 * 40];
    __shared__ int tok[64];

    const int r  = tid >> 2;
    const int c0 = (tid & 3) * 8;
    const int w  = tid >> 6;
    const int L  = tid & 63;
    const int ml = L & 15;
    const int q  = L >> 4;
    const int kq = q * 8;

    if (GATHER) {
        if (tid < 64) tok[tid] = tokens[m0 + tid];
        __syncthreads();
    }

    const float* af32 = nullptr;
    const unsigned short* abf = nullptr;
    if (GATHER) af32 = (const float*)Aptr + (size_t)tok[r] * K + c0;   // tok read ONCE
    else        abf  = (const unsigned short*)Aptr + (size_t)(m0 + r) * K + c0;
    const unsigned short* bsrc = Bt + (size_t)(bn0 + r) * K + c0;

    // prefetch tile 0
    float4 f0, f1; uint4 ab, bb;
    if (GATHER) { f0 = *(const float4*)af32; f1 = *(const float4*)(af32 + 4); af32 += 32; }
    else        { ab = *(const uint4*)abf; abf += 32; }
    bb = *(const uint4*)bsrc; bsrc += 32;

    f32x4 acc[4] = {};

    for (int k0 = 0; k0 < K; k0 += 32) {
        unsigned short tmp[8];
        if (GATHER) {
            tmp[0]=f2bf(f0.x); tmp[1]=f2bf(f0.y); tmp[2]=f2bf(f0.z); tmp[3]=f2bf(f0.w);
            tmp[4]=f2bf(f1.x); tmp[5]=f2bf(f1.y); tmp[6]=f2bf(f1.z); tmp[7]=f2bf(f1.w);
        } else {
            *(uint4*)tmp = ab;
        }
        *(uint4*)&As[r * 40 + c0] = *(const uint4*)tmp;
        *(uint4*)&Bs[r * 40 + c0] = bb;
        __syncthreads();

        if (k0 + 32 < K) {   // prefetch next tile under this tile's MFMAs
            if (GATHER) { f0 = *(const float4*)af32; f1 = *(const float4*)(af32 + 4); af32 += 32; }
            else        { ab = *(const uint4*)abf; abf += 32; }
            bb = *(const uint4*)bsrc; bsrc += 32;
        }

        bf16x8 av = *(const bf16x8*)&As[(16 * w + ml) * 40 + kq];
#pragma unroll
        for (int ns = 0; ns < 4; ++ns) {
            bf16x8 bv = *(const bf16x8*)&Bs[(ns * 16 + ml) * 40 + kq];
            acc[ns] = __builtin_amdgcn_mfma_f32_16x16x32_bf16(av, bv, acc[ns], 0, 0, 0);
        }
        __syncthreads();
    }

#pragma unroll
    for (int ns = 0; ns < 4; ++ns) {
        int gn = bn0 + ns * 16 + ml;
        float bv = bias[gn];
#pragma unroll
        for (int rr = 0; rr < 4; ++rr) {
            int gm = m0 + 16 * w + q * 4 + rr;
            C[(size_t)gm * N + gn] = acc[ns][rr] + bv;
        }
    }
}

// ---------- K2: 2-stage cross-CU pipeline, 4-wave blocks, inlined chunk GEMV ----
// 128 blocks x 256 threads (1 wave/SIMD -> the measured-439ns scan regime).
// Producer blocks 0..63 (batch b):
//   layer-1 scan with h1 -> LDS ring slot t%32. Once per 16-tick group (tick j=0,
//   g>0) the SAME scan waves compute p[16(g-1)..16g-1] = h1_chunk @ W2 + b2,
//   streaming W2 fragments from global (L2-hot) in a 2-deep rotation (<=64
//   transient VGPRs; U1 fragments stay resident -> register rule holds).
//   Tick j=8: counted s_waitcnt vmcnt(7) drains the 16 p-stores (leaves the <=7
//   in-flight xw prefetch loads). Tick j=9: tid0 RELEASE flag = 16g.
// ALIAS NOTE (r3 post-mortem): scan loads go through xw_in (__restrict__) and
// p-stores through p_out (__restrict__) -- same buffer, runtime-disjoint (row r
// is stored only after its final read; loads only touch rows ahead of stores).
// Without this the compiler inserts a vmcnt(0) store->load drain EVERY tick.
// Consumer blocks 64..127: r7's passing consumer, idle waves removed.
__global__ __launch_bounds__(256, 1) void rnn_pipe(
    const float* __restrict__ xw_in,          // [64][512][256] f32 (= emb@W1+b1)
    float* __restrict__ p_out,                // same buffer: rows become p = h1@W2+b2
    const unsigned short* __restrict__ U1t,   // [256][256] bf16 [n][k]
    const unsigned short* __restrict__ W2t,   // [256][256] bf16 [n][k]
    const unsigned short* __restrict__ U2t,   // [256][256] bf16 [n][k]
    const float* __restrict__ b2,             // [256]
    int* flags,                               // [64], zeroed before launch
    float* __restrict__ out_last)             // [64][256] f32
{
    const int bid = blockIdx.x;
    const int tid = threadIdx.x;
    const int w   = tid >> 6;       // 0..3
    const int L   = tid & 63;
    const int col = tid;
    const int q   = L >> 4;
    const int ml  = L & 15;

    __shared__ unsigned short ring[32][256];   // producer: h1 ring / consumer: hsh

    if (bid < 64) {
        // ================= producer =================
        const int b = bid;
        int* flagp = flags + b;

        bf16x8 U1f[4][8];                      // resident fragment set (ONE per wave)
#pragma unroll
        for (int i = 0; i < 4; ++i) {
            const unsigned short* up = U1t + (size_t)((w * 4 + i) * 16 + ml) * 256 + q * 8;
#pragma unroll
            for (int kt = 0; kt < 8; ++kt)
                U1f[i][kt] = *(const bf16x8*)(up + kt * 32);
        }
        ring[31][tid] = 0;                     // h1[-1] = 0

        const float* xpf = xw_in + (size_t)b * 512 * 256 + col;
        float xq[4];
        xq[0] = xpf[0]; xq[1] = xpf[256]; xq[2] = xpf[512]; xq[3] = xpf[768];
        xpf += 4 * 256;
        float b2v[4];
#pragma unroll
        for (int i = 0; i < 4; ++i) b2v[i] = b2[w * 64 + i * 16 + ml];
        float* pb = p_out + (size_t)b * 512 * 256;
        const unsigned short* wbase = W2t + (size_t)((w * 4) * 16 + ml) * 256 + q * 8;
        __syncthreads();

// chunked GEMV: p rows T0..T0+15 from ring half SRCH, W2 streamed 2-deep from global
#define GEMV_CHUNK(SRCH, T0)                                                         \
    {                                                                                \
        bf16x8 wf0[8], wf1[8], afg[8];                                               \
        _Pragma("unroll")                                                            \
        for (int kt = 0; kt < 8; ++kt) wf0[kt] = *(const bf16x8*)(wbase + kt * 32);  \
        _Pragma("unroll")                                                            \
        for (int kt = 0; kt < 8; ++kt) wf1[kt] = *(const bf16x8*)(wbase + 16 * 256 + kt * 32); \
        _Pragma("unroll")                                                            \
        for (int kt = 0; kt < 8; ++kt)                                               \
            afg[kt] = *(const bf16x8*)&ring[(SRCH) * 16 + ml][kt * 32 + q * 8];      \
        f32x4 ac0 = {}, ac1 = {}, ac2 = {}, ac3 = {};                                \
        _Pragma("unroll")                                                            \
        for (int kt = 0; kt < 8; ++kt)                                               \
            ac0 = __builtin_amdgcn_mfma_f32_16x16x32_bf16(afg[kt], wf0[kt], ac0, 0, 0, 0); \
        _Pragma("unroll")                                                            \
        for (int kt = 0; kt < 8; ++kt) wf0[kt] = *(const bf16x8*)(wbase + 32 * 256 + kt * 32); \
        _Pragma("unroll")                                                            \
        for (int kt = 0; kt < 8; ++kt)                                               \
            ac1 = __builtin_amdgcn_mfma_f32_16x16x32_bf16(afg[kt], wf1[kt], ac1, 0, 0, 0); \
        _Pragma("unroll")                                                            \
        for (int kt = 0; kt < 8; ++kt) wf1[kt] = *(const bf16x8*)(wbase + 48 * 256 + kt * 32); \
        _Pragma("unroll")                                                            \
        for (int kt = 0; kt < 8; ++kt)                                               \
            ac2 = __builtin_amdgcn_mfma_f32_16x16x32_bf16(afg[kt], wf0[kt], ac2, 0, 0, 0); \
        _Pragma("unroll")                                                            \
        for (int kt = 0; kt < 8; ++kt)                                               \
            ac3 = __builtin_amdgcn_mfma_f32_16x16x32_bf16(afg[kt], wf1[kt], ac3, 0, 0, 0); \
        float* ps = pb + (size_t)(T0) * 256 + q * 1024 + w * 64 + ml;                \
        _Pragma("unroll")                                                            \
        for (int rr = 0; rr < 4; ++rr) {                                             \
            ps[rr * 256 +  0] = ac0[rr] + b2v[0];                                    \
            ps[rr * 256 + 16] = ac1[rr] + b2v[1];                                    \
            ps[rr * 256 + 32] = ac2[rr] + b2v[2];                                    \
            ps[rr * 256 + 48] = ac3[rr] + b2v[3];                                    \
        }                                                                            \
    }

        for (int g = 0; g < 32; ++g) {
            const int half = g & 1;
#pragma unroll
            for (int j = 0; j < 16; ++j) {
                if (j == 0 && g > 0)
                    GEMV_CHUNK(half ^ 1, (g - 1) * 16)
                if (j == 8)   // drain this wave's 16 p-stores; keep prefetches in flight
                    asm volatile("s_waitcnt vmcnt(7)" ::: "memory");

                // -------- scan tick t = 16g + j --------
                const int slot_r = (j == 0) ? ((half ^ 1) * 16 + 15) : (half * 16 + j - 1);
                bf16x8 af[8];
#pragma unroll
                for (int kt = 0; kt < 8; ++kt)
                    af[kt] = *(const bf16x8*)&ring[slot_r][kt * 32 + q * 8];
                float xnew = *xpf; xpf += 256;   // unconditional; tail overreads stay in ws
                f32x4 accA[4] = {}, accB[4] = {};
#pragma unroll
                for (int kt = 0; kt < 8; kt += 2) {
#pragma unroll
                    for (int i = 0; i < 4; ++i)
                        accA[i] = __builtin_amdgcn_mfma_f32_16x16x32_bf16(af[kt], U1f[i][kt], accA[i], 0, 0, 0);
#pragma unroll
                    for (int i = 0; i < 4; ++i)
                        accB[i] = __builtin_amdgcn_mfma_f32_16x16x32_bf16(af[kt + 1], U1f[i][kt + 1], accB[i], 0, 0, 0);
                }
                float z  = selq(accA, q) + selq(accB, q) + xq[j & 3];
                float e  = __expf(2.f * z);       /* tanh(z) = 1 - 2/(e^{2z}+1) */
                float hn = 1.f - 2.f * __builtin_amdgcn_rcpf(e + 1.f);
                ring[half * 16 + j][col] = f2bf(hn);
                xq[j & 3] = xnew;

                if (j == 9 && g > 0 && tid == 0)
                    __hip_atomic_store(flagp, 16 * g, __ATOMIC_RELEASE, __HIP_MEMORY_SCOPE_AGENT);
                barrier_lds_only();
            }
        }
        // tail: chunk 31 (rows 496..511 from ring slots 16..31)
        GEMV_CHUNK(1, 496)
#undef GEMV_CHUNK
        asm volatile("s_waitcnt vmcnt(0)" ::: "memory");
        __builtin_amdgcn_s_barrier();
        if (tid == 0)
            __hip_atomic_store(flagp, 512, __ATOMIC_RELEASE, __HIP_MEMORY_SCOPE_AGENT);

    } else {
        // ================= consumer (r7's passing code, 4 waves) =================
        const int b = bid - 64;
        int* flagp = flags + b;
        unsigned short (*hsh)[256] = ring;

        bf16x8 Bf[4][8];   // U2 fragments
#pragma unroll
        for (int i = 0; i < 4; ++i) {
            const unsigned short* up = U2t + (size_t)((w * 4 + i) * 16 + ml) * 256 + q * 8;
#pragma unroll
            for (int kt = 0; kt < 8; ++kt)
                Bf[i][kt] = *(const bf16x8*)(up + kt * 32);
        }
        hsh[0][tid] = 0;
        const float* pbc = p_out + (size_t)b * 512 * 256 + col;
        float lastv = 0.f;
        __syncthreads();

#define CTICK(RP, PV)                                                                \
    {                                                                                \
        bf16x8 af[8];                                                                \
        _Pragma("unroll")                                                            \
        for (int kt = 0; kt < 8; ++kt)                                               \
            af[kt] = *(const bf16x8*)&hsh[RP][kt * 32 + q * 8];                     \
        f32x4 accA[4] = {}, accB[4] = {};                                            \
        _Pragma("unroll")                                                            \
        for (int kt = 0; kt < 8; kt += 2) {                                          \
            _Pragma("unroll")                                                        \
            for (int i = 0; i < 4; ++i)                                              \
                accA[i] = __builtin_amdgcn_mfma_f32_16x16x32_bf16(af[kt], Bf[i][kt], accA[i], 0, 0, 0);       \
            _Pragma("unroll")                                                        \
            for (int i = 0; i < 4; ++i)                                              \
                accB[i] = __builtin_amdgcn_mfma_f32_16x16x32_bf16(af[kt + 1], Bf[i][kt + 1], accB[i], 0, 0, 0); \
        }                                                                            \
        float z  = selq(accA, q) + selq(accB, q) + (PV);                             \
        float e  = __expf(2.f * z);                                                  \
        float hn = 1.f - 2.f * __builtin_amdgcn_rcpf(e + 1.f);                       \
        lastv = hn;                                                                  \
        hsh[(RP) ^ 1][col] = f2bf(hn);                                               \
        barrier_lds_only();                                                          \
    }

        for (int c = 0; c < 32; ++c) {
            const int t0 = c * 16;
            if (tid == 0) {
                int it = 0;   // bounded spin: failure => wrong answer, never a hang
                while (__hip_atomic_load(flagp, __ATOMIC_ACQUIRE, __HIP_MEMORY_SCOPE_AGENT) < t0 + 16) {
                    __builtin_amdgcn_s_sleep(2);
                    if (++it > (1 << 17)) break;
                }
            }
            __syncthreads();
            float pv[16];
#pragma unroll
            for (int j = 0; j < 16; ++j)
                pv[j] = pbc[(size_t)(t0 + j) << 8];
            CTICK(0, pv[0])  CTICK(1, pv[1])  CTICK(0, pv[2])  CTICK(1, pv[3])
            CTICK(0, pv[4])  CTICK(1, pv[5])  CTICK(0, pv[6])  CTICK(1, pv[7])
            CTICK(0, pv[8])  CTICK(1, pv[9])  CTICK(0, pv[10]) CTICK(1, pv[11])
            CTICK(0, pv[12]) CTICK(1, pv[13]) CTICK(0, pv[14]) CTICK(1, pv[15])
        }
#undef CTICK

        out_last[b * 256 + col] = lastv;
    }
}

// ---------- head: softmax(h2 @ Wd + bd) ----------
__global__ void head_kernel(const float* __restrict__ h2, const float* __restrict__ Wd,
                            const float* __restrict__ bd, float* __restrict__ out)
{
    int tid = threadIdx.x;         // 128 threads: b = tid>>1, c = tid&1
    int b = tid >> 1, c = tid & 1;
    float s = bd[c];
    for (int jj = 0; jj < 256; ++jj) s = fmaf(h2[b * 256 + jj], Wd[jj * 2 + c], s);
    __shared__ float lg[128];
    lg[tid] = s;
    __syncthreads();
    float o0 = lg[b * 2 + 0], o1 = lg[b * 2 + 1];
    float m = fmaxf(o0, o1);
    float z = __expf(o0 - m) + __expf(o1 - m);
    out[tid] = __expf(s - m) * __builtin_amdgcn_rcpf(z);
}

// ---------- launch ----------
extern "C" void kernel_launch(void* const* d_in, const int* in_sizes, int n_in,
                              void* d_out, int out_size, void* d_ws, size_t ws_size,
                              hipStream_t stream) {
    const int*   tokens = (const int*)d_in[0];
    const float* emb    = (const float*)d_in[1];
    const float* W1     = (const float*)d_in[2];
    const float* U1     = (const float*)d_in[3];
    const float* b1     = (const float*)d_in[4];
    const float* W2     = (const float*)d_in[5];
    const float* U2     = (const float*)d_in[6];
    const float* b2     = (const float*)d_in[7];
    const float* Wd     = (const float*)d_in[8];
    const float* bd     = (const float*)d_in[9];
    float* out = (float*)d_out;

    char* ws = (char*)d_ws;
    float*          xw  = (float*)ws;                                  // 32 MB (xw1 -> p in place)
    char*           p   = ws + 33554432 + 16777216;                    // weights (unchanged offsets)
    unsigned short* W1t = (unsigned short*)p;            p += 512 * 256 * 2;
    unsigned short* W2t = (unsigned short*)p;            p += 256 * 256 * 2;
    unsigned short* U1t = (unsigned short*)p;            p += 256 * 256 * 2;
    unsigned short* U2t = (unsigned short*)p;            p += 256 * 256 * 2;
    float*          h2  = (float*)p;                     p += 64 * 256 * 4;
    int*            flags = (int*)p;                     // 64 ints

    const int M = 64 * 512;   // 32768

    // flags must be 0 before the pipeline kernel (graph-capture-safe async memset)
    hipMemsetAsync(flags, 0, 64 * sizeof(int), stream);

    // K0: weight/recurrence transposes to bf16 [N][K]
    transpose4<<<dim3(512, 4), 256, 0, stream>>>(W1, W2, U1, U2, W1t, W2t, U1t, U2t);

    // K1: xw1 = emb[tokens] @ W1 + b1   (gather fused, prefetch-pipelined)
    gemm_mfma<true><<<dim3(256 / 64, M / 64), 256, 0, stream>>>(
        emb, tokens, W1t, b1, xw, M, 256, 512);

    // K2: 2-stage pipeline (4-wave blocks): scan1 + inlined chunk GEMV -> p -> scan2
    rnn_pipe<<<128, 256, 0, stream>>>(xw, xw, U1t, W2t, U2t, b2, flags, h2);

    // K3: softmax(h2 @ Wd + bd)
    head_kernel<<<1, 128, 0, stream>>>(h2, Wd, bd, out);
}